// Round 4
// baseline (914.935 us; speedup 1.0000x reference)
//
#include <hip/hip_runtime.h>
#include <math.h>

#define DEV __device__ __forceinline__

typedef short bf16x8 __attribute__((ext_vector_type(8)));
typedef float f32x4 __attribute__((ext_vector_type(4)));

DEV float bf2f(short s){
  union{ float f; unsigned u; } v; v.u = ((unsigned)(unsigned short)s) << 16; return v.f;
}
DEV short f2b(float f){ // round-to-nearest-even bf16
  union{ float f; unsigned u; } v; v.f = f;
  unsigned r = v.u + 0x7fffu + ((v.u >> 16) & 1u);
  return (short)(r >> 16);
}
DEV unsigned pk2(float a, float b){ // RNE pack, low short = a
  return ((unsigned)(unsigned short)f2b(b) << 16) | (unsigned short)f2b(a);
}
DEV unsigned pk2t(float a, float b){ // truncating pack via v_perm, low short = a
  union{ float f; unsigned u; } ua, ub; ua.f = a; ub.f = b;
  return __builtin_amdgcn_perm(ub.u, ua.u, 0x07060302);
}

DEV void gll16(const void* g, void* l){
  __builtin_amdgcn_global_load_lds((const __attribute__((address_space(1))) void*)g,
                                   (__attribute__((address_space(3))) void*)l, 16, 0, 0);
}

// ---------------- transpose + (optional) hi/lo split:  in[R][C] f32 -> out[C][R] bf16 ----
template<bool SPLIT>
__global__ void tsplit_kernel(const float* __restrict__ in, short* __restrict__ hi,
                              short* __restrict__ lo, int R, int C){
  __shared__ float tile[32][33];
  int tc = blockIdx.x*32, tr = blockIdx.y*32;
  int lx = threadIdx.x, ly = threadIdx.y;      // 32 x 8
  for (int i = 0; i < 32; i += 8)
    tile[ly+i][lx] = in[(size_t)(tr+ly+i)*C + tc+lx];
  __syncthreads();
  for (int i = 0; i < 32; i += 8){
    float v = tile[lx][ly+i];                  // = in[tr+lx][tc+ly+i]
    size_t o = (size_t)(tc+ly+i)*R + tr+lx;
    short h_ = f2b(v); hi[o] = h_;
    if constexpr (SPLIT) lo[o] = f2b(v - bf2f(h_));
  }
}

// ---------------- layernorm over D=1024, optional hi/lo split output -------------------
template<bool SPLIT>
__global__ void ln_kernel(const float* __restrict__ x, const float* __restrict__ g,
                          const float* __restrict__ bta, short* __restrict__ hi,
                          short* __restrict__ lo){
  int row = blockIdx.x, tid = threadIdx.x;
  const float* xr = x + (size_t)row*1024;
  float v[4], s = 0.f, q = 0.f;
  #pragma unroll
  for (int i = 0; i < 4; i++){ v[i] = xr[tid + i*256]; s += v[i]; q += v[i]*v[i]; }
  #pragma unroll
  for (int m = 1; m < 64; m <<= 1){ s += __shfl_xor(s, m); q += __shfl_xor(q, m); }
  __shared__ float red[8];
  int wave = tid >> 6, lane = tid & 63;
  if (lane == 0){ red[wave] = s; red[4+wave] = q; }
  __syncthreads();
  s = red[0]+red[1]+red[2]+red[3];
  q = red[4]+red[5]+red[6]+red[7];
  float mu = s * (1.f/1024.f);
  float var = q * (1.f/1024.f) - mu*mu;
  float rstd = rsqrtf(var + 1e-5f);
  #pragma unroll
  for (int i = 0; i < 4; i++){
    int d = tid + i*256;
    float z = (v[i]-mu)*rstd*g[d] + bta[d];
    short h_ = f2b(z);
    hi[(size_t)row*1024 + d] = h_;
    if constexpr (SPLIT) lo[(size_t)row*1024 + d] = f2b(z - bf2f(h_));
  }
}

// ---------------- GEMM: C[M,N] = A[M,K] @ BT[N,K]^T, epilogue by MODE -------------------
// MODE 0: split-precision QK, scatter to q/k (hi,lo; [n,h,t,dk]; Q pre-scaled by 1/8)
// MODE 1: outf = res + acc                      (fp32)
// MODE 2: outb = gelu_erf(acc + bias)           (bf16)
// MODE 3: outf = res + acc + bias               (fp32)
// MODE 4: plain V epilogue -> v^T ([n,h,dk,t])
constexpr int BM = 128, BN = 128, BK = 32;

template<int MODE, bool SPLIT>
__global__ __launch_bounds__(256, 2) void gemm_kernel(
    const short* __restrict__ Ahi, const short* __restrict__ Alo,
    const short* __restrict__ Bhi, const short* __restrict__ Blo,
    int M, int N, int K,
    float* __restrict__ outf, short* __restrict__ outb,
    const float* __restrict__ res, const float* __restrict__ bias,
    short* __restrict__ qhi, short* __restrict__ qlo,
    short* __restrict__ khi, short* __restrict__ klo,
    short* __restrict__ vbf)
{
  __shared__ short lds[(SPLIT ? 4 : 2) * BM * BK];
  short* sAhi = lds;
  short* sBhi = lds + BM*BK;
  short* sAlo = lds;
  short* sBlo = lds;
  if constexpr (SPLIT){ sAlo = lds + 2*BM*BK; sBlo = lds + 3*BM*BK; }

  const int tid = threadIdx.x;
  const int wave = tid >> 6, lane = tid & 63;
  const int bm = blockIdx.y * BM, bn = blockIdx.x * BN;
  const int wm = (wave >> 1) * 64, wn = (wave & 1) * 64;

  f32x4 acc[4][4] = {};

  const int srow = lane >> 2;           // 0..15 within a 16-row segment
  const int skq  = (lane & 3) * 8;      // k offset (8 bf16 = 16B)

  for (int k0 = 0; k0 < K; k0 += BK){
    #pragma unroll
    for (int i = 0; i < 2; i++){
      int seg = wave*2 + i;             // 0..7, 16 rows each
      int row = seg*16 + srow;
      gll16(Ahi + (size_t)(bm+row)*K + k0 + skq, sAhi + seg*16*BK);
      gll16(Bhi + (size_t)(bn+row)*K + k0 + skq, sBhi + seg*16*BK);
      if constexpr (SPLIT){
        gll16(Alo + (size_t)(bm+row)*K + k0 + skq, sAlo + seg*16*BK);
        gll16(Blo + (size_t)(bn+row)*K + k0 + skq, sBlo + seg*16*BK);
      }
    }
    __syncthreads();    // vmcnt(0) drain: staging visible
    bf16x8 ah[4], bh[4], al[4], bl[4];
    #pragma unroll
    for (int i = 0; i < 4; i++){
      int ra = (wm + i*16 + (lane & 15)) * BK + (lane >> 4) * 8;
      int rb = (wn + i*16 + (lane & 15)) * BK + (lane >> 4) * 8;
      ah[i] = *(const bf16x8*)&sAhi[ra];
      bh[i] = *(const bf16x8*)&sBhi[rb];
      if constexpr (SPLIT){
        al[i] = *(const bf16x8*)&sAlo[ra];
        bl[i] = *(const bf16x8*)&sBlo[rb];
      }
    }
    __syncthreads();    // frag reads done; next staging may overwrite
    #pragma unroll
    for (int i = 0; i < 4; i++)
      #pragma unroll
      for (int j = 0; j < 4; j++){
        acc[i][j] = __builtin_amdgcn_mfma_f32_16x16x32_bf16(ah[i], bh[j], acc[i][j], 0, 0, 0);
        if constexpr (SPLIT){
          acc[i][j] = __builtin_amdgcn_mfma_f32_16x16x32_bf16(ah[i], bl[j], acc[i][j], 0, 0, 0);
          acc[i][j] = __builtin_amdgcn_mfma_f32_16x16x32_bf16(al[i], bh[j], acc[i][j], 0, 0, 0);
        }
      }
  }

  // epilogue; C/D layout: col = lane&15, row = (lane>>4)*4 + r   [measured m89/m91]
  const int row0 = bm + wm + (lane >> 4) * 4;
  const int col0 = bn + wn + (lane & 15);
  #pragma unroll
  for (int i = 0; i < 4; i++)
    #pragma unroll
    for (int j = 0; j < 4; j++){
      int col = col0 + j*16;
      #pragma unroll
      for (int r = 0; r < 4; r++){
        int row = row0 + i*16 + r;
        float v = acc[i][j][r];
        if constexpr (MODE == 1){
          size_t o = (size_t)row*N + col;
          outf[o] = res[o] + v;
        } else if constexpr (MODE == 2){
          float t = v + bias[col];
          t = 0.5f * t * (1.0f + erff(t * 0.70710678118654752f));
          outb[(size_t)row*N + col] = f2b(t);
        } else if constexpr (MODE == 3){
          size_t o = (size_t)row*N + col;
          outf[o] = res[o] + v + bias[col];
        } else if constexpr (MODE == 4){
          int nb = row >> 11, tt = row & 2047;
          int hh = col >> 6, dk = col & 63;
          vbf[((size_t)(nb*16 + hh)*64 + dk)*2048 + tt] = f2b(v);
        } else {
          int nb = row >> 11, tt = row & 2047;   // T = 2048
          if (col < 1024){
            int h = col >> 6, dk = col & 63;
            size_t o = ((size_t)(nb*16 + h)*2048 + tt)*64 + dk;
            float vq = v * 0.125f;               // fold 1/sqrt(dk) into Q
            short h_ = f2b(vq); qhi[o] = h_; qlo[o] = f2b(vq - bf2f(h_));
          } else {
            int c = col - 1024, h = c >> 6, dk = c & 63;
            size_t o = ((size_t)(nb*16 + h)*2048 + tt)*64 + dk;
            short h_ = f2b(v); khi[o] = h_; klo[o] = f2b(v - bf2f(h_));
          }
        }
      }
    }
}

// ---------------- flash attention v3: K in LDS, V direct-global, 48 KB LDS -------------
// 64 Q-rows/block (16/wave), 128-key tiles. S^T = K*Q^T so each lane owns one Q-row's
// softmax stats. P is wave-private LDS. V read straight from global as A-frags (L2-hot).
__global__ __launch_bounds__(256, 3) void attn_kernel(
    const short* __restrict__ qhi, const short* __restrict__ qlo,
    const short* __restrict__ khi, const short* __restrict__ klo,
    const short* __restrict__ vt,  const float* __restrict__ mask,
    short* __restrict__ ctx)
{
  __shared__ short sKh[128*64];   // 16 KB  K hi  [kt][dk] swizzled
  __shared__ short sKl[128*64];   // 16 KB  K lo
  __shared__ short sP[4*16*128];  // 16 KB  per-wave P^T B-frag buf; Q staged here first
  short* sQh = sP;                // 64x64
  short* sQl = sP + 4096;         // 64x64

  const int tid = threadIdx.x, wave = tid >> 6, lane = tid & 63;
  const int qd = lane >> 4, n16 = lane & 15;
  const int nh = blockIdx.x, nb = nh >> 4, h = nh & 15;  // x = nh: bid%8 = nh%8 -> XCD-local K/V
  const int q0 = blockIdx.y * 64;
  const size_t qoff = ((size_t)nh*2048 + q0)*64;
  const int sw = n16 & 7;

  // ---- stage Q hi/lo into sP region (swizzled) ----
  {
    int cg = ((lane & 7) ^ (lane >> 3)) * 8;
    int rowl = lane >> 3;
    #pragma unroll
    for (int i = 0; i < 2; i++){
      int seg = wave*2 + i;
      int row = seg*8 + rowl;
      gll16(qhi + qoff + (size_t)row*64 + cg, sQh + seg*512);
      gll16(qlo + qoff + (size_t)row*64 + cg, sQl + seg*512);
    }
  }
  __syncthreads();

  // ---- Q B-frags ----
  bf16x8 bqh[2], bql[2];
  #pragma unroll
  for (int k2 = 0; k2 < 2; k2++){
    int off = (wave*16 + n16)*64 + (((k2*4 + qd) ^ sw) << 3);
    bqh[k2] = *(const bf16x8*)&sQh[off];
    bql[k2] = *(const bf16x8*)&sQl[off];
  }
  // first in-loop barrier guarantees all Q reads complete before any P write

  float m_i = -1e30f, l_i = 0.f;
  f32x4 o_[4] = {};
  short* myP = sP + wave*2048;
  const float4* mask4 = (const float4*)(mask + (size_t)nb*2048);
  const short* vbaseh = vt + ((size_t)nh*64)*2048;

  for (int kt = 0; kt < 2048; kt += 128){
    const size_t koff = ((size_t)nh*2048 + kt)*64;
    // ---- stage K hi/lo (128x64), swizzled ----
    {
      int cg = ((lane & 7) ^ (lane >> 3)) * 8;
      int rowl = lane >> 3;
      #pragma unroll
      for (int i = 0; i < 4; i++){
        int seg = wave*4 + i;
        int row = seg*8 + rowl;
        gll16(khi + koff + (size_t)row*64 + cg, sKh + seg*512);
        gll16(klo + koff + (size_t)row*64 + cg, sKl + seg*512);
      }
    }
    __syncthreads();   // staging visible (also fences Q reads / prior-tile P reads)

    // ---- S^T = K * Q^T (split: KhQh + KhQl + KlQh); row=kt_loc, col=qrow ----
    f32x4 sc[8];
    #pragma unroll
    for (int j = 0; j < 8; j++){
      f32x4 z = {};
      #pragma unroll
      for (int k2 = 0; k2 < 2; k2++){
        int off = (j*16 + n16)*64 + (((k2*4 + qd) ^ sw) << 3);
        bf16x8 akh = *(const bf16x8*)&sKh[off];
        bf16x8 akl = *(const bf16x8*)&sKl[off];
        z = __builtin_amdgcn_mfma_f32_16x16x32_bf16(akh, bqh[k2], z, 0, 0, 0);
        z = __builtin_amdgcn_mfma_f32_16x16x32_bf16(akh, bql[k2], z, 0, 0, 0);
        z = __builtin_amdgcn_mfma_f32_16x16x32_bf16(akl, bqh[k2], z, 0, 0, 0);
      }
      sc[j] = z;
    }

    // ---- online softmax: lane owns Q-row n16; kt_loc = j*16 + qd*4 + r ----
    float mloc = -1e30f;
    #pragma unroll
    for (int j = 0; j < 8; j++){
      float4 mk = mask4[(kt >> 2) + j*4 + qd];
      const float* mkp = (const float*)&mk;
      #pragma unroll
      for (int r = 0; r < 4; r++){
        float s = sc[j][r] + mkp[r];
        sc[j][r] = s;
        mloc = fmaxf(mloc, s);
      }
    }
    mloc = fmaxf(mloc, __shfl_xor(mloc, 16, 64));
    mloc = fmaxf(mloc, __shfl_xor(mloc, 32, 64));
    float mnew = fmaxf(m_i, mloc);
    float alpha = __expf(m_i - mnew);
    m_i = mnew;
    float ps = 0.f;
    #pragma unroll
    for (int j = 0; j < 8; j++)
      #pragma unroll
      for (int r = 0; r < 4; r++){
        float p = __expf(sc[j][r] - mnew);
        sc[j][r] = p;
        ps += p;
      }
    ps += __shfl_xor(ps, 16, 64);
    ps += __shfl_xor(ps, 32, 64);
    l_i = l_i*alpha + ps;
    #pragma unroll
    for (int c = 0; c < 4; c++)
      #pragma unroll
      for (int r = 0; r < 4; r++) o_[c][r] *= alpha;

    // ---- P^T -> per-wave LDS B-frag layout [qrow][kt], swizzled; no barrier ----
    #pragma unroll
    for (int b = 0; b < 8; b++){
      uint2 w;
      w.x = pk2t(sc[b][0], sc[b][1]);
      w.y = pk2t(sc[b][2], sc[b][3]);
      int off = n16*128 + ((((b*2 + (qd >> 1)) ^ sw)) << 3) + (qd & 1)*4;
      *(uint2*)&myP[off] = w;
    }

    // ---- O^T += V^T * P^T  (V A-frags direct from global, L2-hot) ----
    #pragma unroll
    for (int kq = 0; kq < 4; kq++){
      bf16x8 bp = *(const bf16x8*)&myP[n16*128 + (((kq*4 + qd) ^ sw) << 3)];
      #pragma unroll
      for (int c = 0; c < 4; c++){
        bf16x8 av = *(const bf16x8*)&vbaseh[(size_t)(c*16 + n16)*2048 + kt + kq*32 + qd*8];
        o_[c] = __builtin_amdgcn_mfma_f32_16x16x32_bf16(av, bp, o_[c], 0, 0, 0);
      }
    }
    __syncthreads();   // K/P LDS reads done before next staging
  }

  // ---- epilogue: lane holds O^T[dk = c*16+qd*4+r][qrow = n16] ----
  float linv = 1.0f / l_i;
  int row = q0 + wave*16 + n16;
  size_t base = ((size_t)nb*2048 + row)*1024 + h*64;
  #pragma unroll
  for (int c = 0; c < 4; c++){
    uint2 w;
    w.x = pk2(o_[c][0]*linv, o_[c][1]*linv);
    w.y = pk2(o_[c][2]*linv, o_[c][3]*linv);
    *(uint2*)&ctx[base + c*16 + qd*4] = w;
  }
}

// ---------------------------------------------------------------------------------------
// Workspace arena: 128 MB total via lifetime aliasing.
extern "C" void kernel_launch(void* const* d_in, const int* in_sizes, int n_in,
                              void* d_out, int out_size, void* d_ws, size_t ws_size,
                              hipStream_t stream)
{
  (void)in_sizes; (void)n_in; (void)out_size; (void)ws_size;
  const float* x    = (const float*)d_in[0];
  const float* mask = (const float*)d_in[1];
  const float* Wqkv = (const float*)d_in[2];
  const float* Wout = (const float*)d_in[3];
  const float* ln1g = (const float*)d_in[4];
  const float* ln1b = (const float*)d_in[5];
  const float* ln2g = (const float*)d_in[6];
  const float* ln2b = (const float*)d_in[7];
  const float* W1   = (const float*)d_in[8];
  const float* b1   = (const float*)d_in[9];
  const float* W2   = (const float*)d_in[10];
  const float* b2   = (const float*)d_in[11];
  float* out = (float*)d_out;

  const int M = 8192;  // N*T
  const size_t MB = 1024*1024;
  char* ws = (char*)d_ws;

  short* wqT_h = (short*)(ws + 0*MB);
  short* wqT_l = (short*)(ws + 6*MB);
  short* zhi   = (short*)(ws + 12*MB);
  short* zlo   = (short*)(ws + 28*MB);
  short* qh    = (short*)(ws + 44*MB);
  short* ql    = (short*)(ws + 60*MB);
  short* kh    = (short*)(ws + 76*MB);
  short* kl    = (short*)(ws + 92*MB);
  short* vb    = (short*)(ws + 108*MB);
  short* ctx   = (short*)(ws + 0*MB);     // aliases wq/zhi (dead)
  short* woT   = (short*)(ws + 16*MB);    // aliases zhi (dead)
  float* x2    = (float*)(ws + 64*MB);    // aliases ql/kh/kl (dead)
  short* z2    = (short*)(ws + 96*MB);    // aliases kl/vb (dead)
  short* w1T   = (short*)(ws + 112*MB);   // aliases vb (dead)
  short* w2T   = (short*)(ws + 120*MB);   // aliases vb end (dead)
  short* hbuf  = (short*)(ws + 0*MB);     // aliases ctx/woT/z/qh/ql (dead)

  dim3 tb(32, 8);

  // S1: Wqkv transpose+split; S2: LN1
  tsplit_kernel<true ><<<dim3(3072/32, 1024/32), tb, 0, stream>>>(Wqkv, wqT_h, wqT_l, 1024, 3072);
  ln_kernel<true ><<<dim3(M), dim3(256), 0, stream>>>(x, ln1g, ln1b, zhi, zlo);

  // S3a: QK split-GEMM (N=2048) -> qh/ql/kh/kl  (Q pre-scaled by 1/8)
  gemm_kernel<0, true><<<dim3(2048/128, M/128), dim3(256), 0, stream>>>(
      zhi, zlo, wqT_h, wqT_l, M, 2048, 1024,
      nullptr, nullptr, nullptr, nullptr,
      qh, ql, kh, kl, nullptr);

  // S3b: V plain GEMM (N=1024) -> vb
  gemm_kernel<4, false><<<dim3(1024/128, M/128), dim3(256), 0, stream>>>(
      zhi, nullptr, wqT_h + (size_t)2048*1024, nullptr, M, 1024, 1024,
      nullptr, nullptr, nullptr, nullptr,
      nullptr, nullptr, nullptr, nullptr, vb);

  // S3.5: Wout transpose (writes over dead zhi region)
  tsplit_kernel<false><<<dim3(1024/32, 1024/32), tb, 0, stream>>>(Wout, woT, nullptr, 1024, 1024);

  // S4: flash attention -> ctx (grid.x = nh for XCD L2 locality)
  attn_kernel<<<dim3(64, 2048/64), dim3(256), 0, stream>>>(qh, ql, kh, kl, vb, mask, ctx);

  // S4.5: W1/W2 transposes (write over dead vb region — must follow attn)
  tsplit_kernel<false><<<dim3(4096/32, 1024/32), tb, 0, stream>>>(W1, w1T, nullptr, 1024, 4096);
  tsplit_kernel<false><<<dim3(1024/32, 4096/32), tb, 0, stream>>>(W2, w2T, nullptr, 4096, 1024);

  // S5: attn_out @ Wout + residual -> x2
  gemm_kernel<1, false><<<dim3(1024/128, M/128), dim3(256), 0, stream>>>(
      ctx, nullptr, woT, nullptr, M, 1024, 1024,
      x2, nullptr, x, nullptr,
      nullptr, nullptr, nullptr, nullptr, nullptr);

  // S6: LN2 -> z2
  ln_kernel<false><<<dim3(M), dim3(256), 0, stream>>>(x2, ln2g, ln2b, z2, nullptr);

  // S7: GELU(z2 @ W1 + b1) -> hbuf
  gemm_kernel<2, false><<<dim3(4096/128, M/128), dim3(256), 0, stream>>>(
      z2, nullptr, w1T, nullptr, M, 4096, 1024,
      nullptr, hbuf, nullptr, b1,
      nullptr, nullptr, nullptr, nullptr, nullptr);

  // S8: hbuf @ W2 + b2 + x2 -> out
  gemm_kernel<3, false><<<dim3(1024/128, M/128), dim3(256), 0, stream>>>(
      hbuf, nullptr, w2T, nullptr, M, 1024, 4096,
      out, nullptr, x2, b2,
      nullptr, nullptr, nullptr, nullptr, nullptr);
}

// Round 5
// 684.154 us; speedup vs baseline: 1.3373x; 1.3373x over previous
//
#include <hip/hip_runtime.h>
#include <math.h>

#define DEV __device__ __forceinline__

typedef short bf16x8 __attribute__((ext_vector_type(8)));
typedef float f32x4 __attribute__((ext_vector_type(4)));

DEV float bf2f(short s){
  union{ float f; unsigned u; } v; v.u = ((unsigned)(unsigned short)s) << 16; return v.f;
}
DEV short f2b(float f){ // round-to-nearest-even bf16
  union{ float f; unsigned u; } v; v.f = f;
  unsigned r = v.u + 0x7fffu + ((v.u >> 16) & 1u);
  return (short)(r >> 16);
}
DEV unsigned pk2(float a, float b){ // RNE pack, low short = a
  return ((unsigned)(unsigned short)f2b(b) << 16) | (unsigned short)f2b(a);
}
DEV unsigned pk2t(float a, float b){ // truncating pack via v_perm, low short = a
  union{ float f; unsigned u; } ua, ub; ua.f = a; ub.f = b;
  return __builtin_amdgcn_perm(ub.u, ua.u, 0x07060302);
}

DEV void gll16(const void* g, void* l){
  __builtin_amdgcn_global_load_lds((const __attribute__((address_space(1))) void*)g,
                                   (__attribute__((address_space(3))) void*)l, 16, 0, 0);
}

// ---------------- transpose + (optional) hi/lo split:  in[R][C] f32 -> out[C][R] bf16 ----
template<bool SPLIT>
__global__ void tsplit_kernel(const float* __restrict__ in, short* __restrict__ hi,
                              short* __restrict__ lo, int R, int C){
  __shared__ float tile[32][33];
  int tc = blockIdx.x*32, tr = blockIdx.y*32;
  int lx = threadIdx.x, ly = threadIdx.y;      // 32 x 8
  for (int i = 0; i < 32; i += 8)
    tile[ly+i][lx] = in[(size_t)(tr+ly+i)*C + tc+lx];
  __syncthreads();
  for (int i = 0; i < 32; i += 8){
    float v = tile[lx][ly+i];                  // = in[tr+lx][tc+ly+i]
    size_t o = (size_t)(tc+ly+i)*R + tr+lx;
    short h_ = f2b(v); hi[o] = h_;
    if constexpr (SPLIT) lo[o] = f2b(v - bf2f(h_));
  }
}

// ---------------- layernorm over D=1024, optional hi/lo split output -------------------
template<bool SPLIT>
__global__ void ln_kernel(const float* __restrict__ x, const float* __restrict__ g,
                          const float* __restrict__ bta, short* __restrict__ hi,
                          short* __restrict__ lo){
  int row = blockIdx.x, tid = threadIdx.x;
  const float* xr = x + (size_t)row*1024;
  float v[4], s = 0.f, q = 0.f;
  #pragma unroll
  for (int i = 0; i < 4; i++){ v[i] = xr[tid + i*256]; s += v[i]; q += v[i]*v[i]; }
  #pragma unroll
  for (int m = 1; m < 64; m <<= 1){ s += __shfl_xor(s, m); q += __shfl_xor(q, m); }
  __shared__ float red[8];
  int wave = tid >> 6, lane = tid & 63;
  if (lane == 0){ red[wave] = s; red[4+wave] = q; }
  __syncthreads();
  s = red[0]+red[1]+red[2]+red[3];
  q = red[4]+red[5]+red[6]+red[7];
  float mu = s * (1.f/1024.f);
  float var = q * (1.f/1024.f) - mu*mu;
  float rstd = rsqrtf(var + 1e-5f);
  #pragma unroll
  for (int i = 0; i < 4; i++){
    int d = tid + i*256;
    float z = (v[i]-mu)*rstd*g[d] + bta[d];
    short h_ = f2b(z);
    hi[(size_t)row*1024 + d] = h_;
    if constexpr (SPLIT) lo[(size_t)row*1024 + d] = f2b(z - bf2f(h_));
  }
}

// ---------------- GEMM: C[M,N] = A[M,K] @ BT[N,K]^T, epilogue by MODE -------------------
// MODE 0: split-precision QK, scatter to q/k (hi,lo; [n,h,t,dk]; Q pre-scaled by 1/8)
// MODE 1: outf = res + acc                      (fp32)
// MODE 2: outb = gelu_erf(acc + bias)           (bf16)
// MODE 3: outf = res + acc + bias               (fp32)
// MODE 4: plain V epilogue -> v^T ([n,h,dk,t])
constexpr int BM = 128, BN = 128, BK = 32;

template<int MODE, bool SPLIT>
__global__ __launch_bounds__(256, 2) void gemm_kernel(
    const short* __restrict__ Ahi, const short* __restrict__ Alo,
    const short* __restrict__ Bhi, const short* __restrict__ Blo,
    int M, int N, int K,
    float* __restrict__ outf, short* __restrict__ outb,
    const float* __restrict__ res, const float* __restrict__ bias,
    short* __restrict__ qhi, short* __restrict__ qlo,
    short* __restrict__ khi, short* __restrict__ klo,
    short* __restrict__ vbf)
{
  __shared__ short lds[(SPLIT ? 4 : 2) * BM * BK];
  short* sAhi = lds;
  short* sBhi = lds + BM*BK;
  short* sAlo = lds;
  short* sBlo = lds;
  if constexpr (SPLIT){ sAlo = lds + 2*BM*BK; sBlo = lds + 3*BM*BK; }

  const int tid = threadIdx.x;
  const int wave = tid >> 6, lane = tid & 63;
  const int bm = blockIdx.y * BM, bn = blockIdx.x * BN;
  const int wm = (wave >> 1) * 64, wn = (wave & 1) * 64;

  f32x4 acc[4][4] = {};

  const int srow = lane >> 2;           // 0..15 within a 16-row segment
  const int skq  = (lane & 3) * 8;      // k offset (8 bf16 = 16B)

  for (int k0 = 0; k0 < K; k0 += BK){
    #pragma unroll
    for (int i = 0; i < 2; i++){
      int seg = wave*2 + i;             // 0..7, 16 rows each
      int row = seg*16 + srow;
      gll16(Ahi + (size_t)(bm+row)*K + k0 + skq, sAhi + seg*16*BK);
      gll16(Bhi + (size_t)(bn+row)*K + k0 + skq, sBhi + seg*16*BK);
      if constexpr (SPLIT){
        gll16(Alo + (size_t)(bm+row)*K + k0 + skq, sAlo + seg*16*BK);
        gll16(Blo + (size_t)(bn+row)*K + k0 + skq, sBlo + seg*16*BK);
      }
    }
    __syncthreads();    // vmcnt(0) drain: staging visible
    bf16x8 ah[4], bh[4], al[4], bl[4];
    #pragma unroll
    for (int i = 0; i < 4; i++){
      int ra = (wm + i*16 + (lane & 15)) * BK + (lane >> 4) * 8;
      int rb = (wn + i*16 + (lane & 15)) * BK + (lane >> 4) * 8;
      ah[i] = *(const bf16x8*)&sAhi[ra];
      bh[i] = *(const bf16x8*)&sBhi[rb];
      if constexpr (SPLIT){
        al[i] = *(const bf16x8*)&sAlo[ra];
        bl[i] = *(const bf16x8*)&sBlo[rb];
      }
    }
    __syncthreads();    // frag reads done; next staging may overwrite
    #pragma unroll
    for (int i = 0; i < 4; i++)
      #pragma unroll
      for (int j = 0; j < 4; j++){
        acc[i][j] = __builtin_amdgcn_mfma_f32_16x16x32_bf16(ah[i], bh[j], acc[i][j], 0, 0, 0);
        if constexpr (SPLIT){
          acc[i][j] = __builtin_amdgcn_mfma_f32_16x16x32_bf16(ah[i], bl[j], acc[i][j], 0, 0, 0);
          acc[i][j] = __builtin_amdgcn_mfma_f32_16x16x32_bf16(al[i], bh[j], acc[i][j], 0, 0, 0);
        }
      }
  }

  // epilogue; C/D layout: col = lane&15, row = (lane>>4)*4 + r   [measured m89/m91]
  const int row0 = bm + wm + (lane >> 4) * 4;
  const int col0 = bn + wn + (lane & 15);
  #pragma unroll
  for (int i = 0; i < 4; i++)
    #pragma unroll
    for (int j = 0; j < 4; j++){
      int col = col0 + j*16;
      #pragma unroll
      for (int r = 0; r < 4; r++){
        int row = row0 + i*16 + r;
        float v = acc[i][j][r];
        if constexpr (MODE == 1){
          size_t o = (size_t)row*N + col;
          outf[o] = res[o] + v;
        } else if constexpr (MODE == 2){
          float t = v + bias[col];
          t = 0.5f * t * (1.0f + erff(t * 0.70710678118654752f));
          outb[(size_t)row*N + col] = f2b(t);
        } else if constexpr (MODE == 3){
          size_t o = (size_t)row*N + col;
          outf[o] = res[o] + v + bias[col];
        } else if constexpr (MODE == 4){
          int nb = row >> 11, tt = row & 2047;
          int hh = col >> 6, dk = col & 63;
          vbf[((size_t)(nb*16 + hh)*64 + dk)*2048 + tt] = f2b(v);
        } else {
          int nb = row >> 11, tt = row & 2047;   // T = 2048
          if (col < 1024){
            int h = col >> 6, dk = col & 63;
            size_t o = ((size_t)(nb*16 + h)*2048 + tt)*64 + dk;
            float vq = v * 0.125f;               // fold 1/sqrt(dk) into Q
            short h_ = f2b(vq); qhi[o] = h_; qlo[o] = f2b(vq - bf2f(h_));
          } else {
            int c = col - 1024, h = c >> 6, dk = c & 63;
            size_t o = ((size_t)(nb*16 + h)*2048 + tt)*64 + dk;
            short h_ = f2b(v); khi[o] = h_; klo[o] = f2b(v - bf2f(h_));
          }
        }
      }
    }
}

// ---------------- flash attention v4: 512 thr, 128 Q-rows/block, 48 KB LDS -------------
// K hi/lo + V staged in LDS per 128-key tile; P (32 KB) aliases the K region (all K
// reads complete before P writes — barrier C). S^T = K*Q^T: lane owns one Q-row's stats.
__global__ __launch_bounds__(512, 4) void attn_kernel(
    const short* __restrict__ qhi, const short* __restrict__ qlo,
    const short* __restrict__ khi, const short* __restrict__ klo,
    const short* __restrict__ vt,  const float* __restrict__ mask,
    short* __restrict__ ctx)
{
  __shared__ short lds[3*128*64];  // 48 KB: [0,8192)=Kh, [8192,16384)=Kl, [16384,24576)=V
  short* sKh = lds;                // 128x64 swizzled
  short* sKl = lds + 8192;
  short* sV  = lds + 16384;        // V^T 64x128 swizzled
  short* sQh = sKh;                // Q staged here pre-loop (dead once frags read)
  short* sQl = sKl;

  const int tid = threadIdx.x, wave = tid >> 6, lane = tid & 63;
  const int qd = lane >> 4, n16 = lane & 15;
  const int nh = blockIdx.x, nb = nh >> 4, h = nh & 15;  // bid%8 = nh%8 -> XCD-local K/V
  const int q0 = blockIdx.y * 128;
  const size_t qoff = ((size_t)nh*2048 + q0)*64;
  const int sw = n16 & 7;

  // ---- stage Q hi/lo (128x64 each, swizzled: lds[row][c] = glob[row][c^(row&7)]) ----
  {
    int cg = ((lane & 7) ^ (lane >> 3)) * 8;
    int rowl = lane >> 3;
    #pragma unroll
    for (int i = 0; i < 2; i++){
      int seg = wave*2 + i;          // 0..15, 8 rows each
      int row = seg*8 + rowl;
      gll16(qhi + qoff + (size_t)row*64 + cg, sQh + seg*512);
      gll16(qlo + qoff + (size_t)row*64 + cg, sQl + seg*512);
    }
  }
  __syncthreads();

  // ---- Q B-frags (wave owns rows wave*16 .. wave*16+15) ----
  bf16x8 bqh[2], bql[2];
  #pragma unroll
  for (int k2 = 0; k2 < 2; k2++){
    int off = (wave*16 + n16)*64 + (((k2*4 + qd) ^ sw) << 3);
    bqh[k2] = *(const bf16x8*)&sQh[off];
    bql[k2] = *(const bf16x8*)&sQl[off];
  }
  // loop-top barrier fences these reads before K staging overwrites

  float m_i = -1e30f, l_i = 0.f;
  f32x4 o_[4] = {};
  short* myP = lds + wave*2048;      // 16x128 per wave; 8 waves = 32 KB = Kh∪Kl region
  const float4* mask4 = (const float4*)(mask + (size_t)nb*2048);

  for (int kt = 0; kt < 2048; kt += 128){
    __syncthreads();   // A: prior PV reads (P, sV) + Q-frag reads done
    const size_t koff = ((size_t)nh*2048 + kt)*64;
    {
      int cg = ((lane & 7) ^ (lane >> 3)) * 8;
      int rowl = lane >> 3;
      #pragma unroll
      for (int i = 0; i < 2; i++){
        int seg = wave*2 + i;        // 0..15, 8 K-rows each
        int row = seg*8 + rowl;
        gll16(khi + koff + (size_t)row*64 + cg, sKh + seg*512);
        gll16(klo + koff + (size_t)row*64 + cg, sKl + seg*512);
      }
      #pragma unroll
      for (int i = 0; i < 2; i++){
        int seg = wave*2 + i;        // 0..15, 4 dk-rows each
        int dk = seg*4 + qd;
        int cgv = ((lane & 15) ^ (dk & 7)) * 8;
        gll16(vt + ((size_t)nh*64 + dk)*2048 + kt + cgv, sV + seg*512);
      }
    }
    __syncthreads();   // B: staging visible

    // ---- S^T = K * Q^T (split: KhQh + KhQl + KlQh); row=kt_loc, col=qrow ----
    f32x4 sc[8];
    #pragma unroll
    for (int j = 0; j < 8; j++){
      f32x4 z = {};
      #pragma unroll
      for (int k2 = 0; k2 < 2; k2++){
        int off = (j*16 + n16)*64 + (((k2*4 + qd) ^ sw) << 3);
        bf16x8 akh = *(const bf16x8*)&sKh[off];
        bf16x8 akl = *(const bf16x8*)&sKl[off];
        z = __builtin_amdgcn_mfma_f32_16x16x32_bf16(akh, bqh[k2], z, 0, 0, 0);
        z = __builtin_amdgcn_mfma_f32_16x16x32_bf16(akh, bql[k2], z, 0, 0, 0);
        z = __builtin_amdgcn_mfma_f32_16x16x32_bf16(akl, bqh[k2], z, 0, 0, 0);
      }
      sc[j] = z;
    }

    // ---- online softmax: lane owns Q-row n16; kt_loc = j*16 + qd*4 + r ----
    float mloc = -1e30f;
    #pragma unroll
    for (int j = 0; j < 8; j++){
      float4 mk = mask4[(kt >> 2) + j*4 + qd];
      const float* mkp = (const float*)&mk;
      #pragma unroll
      for (int r = 0; r < 4; r++){
        float s = sc[j][r] + mkp[r];
        sc[j][r] = s;
        mloc = fmaxf(mloc, s);
      }
    }
    mloc = fmaxf(mloc, __shfl_xor(mloc, 16, 64));
    mloc = fmaxf(mloc, __shfl_xor(mloc, 32, 64));
    float mnew = fmaxf(m_i, mloc);
    float alpha = __expf(m_i - mnew);
    m_i = mnew;
    float ps = 0.f;
    #pragma unroll
    for (int j = 0; j < 8; j++)
      #pragma unroll
      for (int r = 0; r < 4; r++){
        float p = __expf(sc[j][r] - mnew);
        sc[j][r] = p;
        ps += p;
      }
    ps += __shfl_xor(ps, 16, 64);
    ps += __shfl_xor(ps, 32, 64);
    l_i = l_i*alpha + ps;
    #pragma unroll
    for (int c = 0; c < 4; c++)
      #pragma unroll
      for (int r = 0; r < 4; r++) o_[c][r] *= alpha;

    __syncthreads();   // C: all waves' K reads done; P may overwrite K region

    // ---- P^T -> per-wave LDS B-frag layout [qrow][kt], swizzled ----
    #pragma unroll
    for (int b = 0; b < 8; b++){
      uint2 w;
      w.x = pk2t(sc[b][0], sc[b][1]);
      w.y = pk2t(sc[b][2], sc[b][3]);
      int off = n16*128 + ((((b*2 + (qd >> 1)) ^ sw)) << 3) + (qd & 1)*4;
      *(uint2*)&myP[off] = w;
    }

    // ---- O^T += V^T * P^T ----
    #pragma unroll
    for (int kq = 0; kq < 4; kq++){
      bf16x8 bp = *(const bf16x8*)&myP[n16*128 + (((kq*4 + qd) ^ sw) << 3)];
      #pragma unroll
      for (int c = 0; c < 4; c++){
        bf16x8 av = *(const bf16x8*)&sV[(c*16 + n16)*128 + (((kq*4 + qd) ^ sw) << 3)];
        o_[c] = __builtin_amdgcn_mfma_f32_16x16x32_bf16(av, bp, o_[c], 0, 0, 0);
      }
    }
  }

  // ---- epilogue: lane holds O^T[dk = c*16+qd*4+r][qrow = n16] ----
  float linv = 1.0f / l_i;
  int row = q0 + wave*16 + n16;
  size_t base = ((size_t)nb*2048 + row)*1024 + h*64;
  #pragma unroll
  for (int c = 0; c < 4; c++){
    uint2 w;
    w.x = pk2(o_[c][0]*linv, o_[c][1]*linv);
    w.y = pk2(o_[c][2]*linv, o_[c][3]*linv);
    *(uint2*)&ctx[base + c*16 + qd*4] = w;
  }
}

// ---------------------------------------------------------------------------------------
// Workspace arena: 128 MB total via lifetime aliasing.
extern "C" void kernel_launch(void* const* d_in, const int* in_sizes, int n_in,
                              void* d_out, int out_size, void* d_ws, size_t ws_size,
                              hipStream_t stream)
{
  (void)in_sizes; (void)n_in; (void)out_size; (void)ws_size;
  const float* x    = (const float*)d_in[0];
  const float* mask = (const float*)d_in[1];
  const float* Wqkv = (const float*)d_in[2];
  const float* Wout = (const float*)d_in[3];
  const float* ln1g = (const float*)d_in[4];
  const float* ln1b = (const float*)d_in[5];
  const float* ln2g = (const float*)d_in[6];
  const float* ln2b = (const float*)d_in[7];
  const float* W1   = (const float*)d_in[8];
  const float* b1   = (const float*)d_in[9];
  const float* W2   = (const float*)d_in[10];
  const float* b2   = (const float*)d_in[11];
  float* out = (float*)d_out;

  const int M = 8192;  // N*T
  const size_t MB = 1024*1024;
  char* ws = (char*)d_ws;

  short* wqT_h = (short*)(ws + 0*MB);
  short* wqT_l = (short*)(ws + 6*MB);
  short* zhi   = (short*)(ws + 12*MB);
  short* zlo   = (short*)(ws + 28*MB);
  short* qh    = (short*)(ws + 44*MB);
  short* ql    = (short*)(ws + 60*MB);
  short* kh    = (short*)(ws + 76*MB);
  short* kl    = (short*)(ws + 92*MB);
  short* vb    = (short*)(ws + 108*MB);
  short* ctx   = (short*)(ws + 0*MB);     // aliases wq/zhi (dead)
  short* woT   = (short*)(ws + 16*MB);    // aliases zhi (dead)
  float* x2    = (float*)(ws + 64*MB);    // aliases ql/kh/kl (dead)
  short* z2    = (short*)(ws + 96*MB);    // aliases kl/vb (dead)
  short* w1T   = (short*)(ws + 112*MB);   // aliases vb (dead)
  short* w2T   = (short*)(ws + 120*MB);   // aliases vb end (dead)
  short* hbuf  = (short*)(ws + 0*MB);     // aliases ctx/woT/z/qh/ql (dead)

  dim3 tb(32, 8);

  // S1: Wqkv transpose+split; S2: LN1
  tsplit_kernel<true ><<<dim3(3072/32, 1024/32), tb, 0, stream>>>(Wqkv, wqT_h, wqT_l, 1024, 3072);
  ln_kernel<true ><<<dim3(M), dim3(256), 0, stream>>>(x, ln1g, ln1b, zhi, zlo);

  // S3a: QK split-GEMM (N=2048) -> qh/ql/kh/kl  (Q pre-scaled by 1/8)
  gemm_kernel<0, true><<<dim3(2048/128, M/128), dim3(256), 0, stream>>>(
      zhi, zlo, wqT_h, wqT_l, M, 2048, 1024,
      nullptr, nullptr, nullptr, nullptr,
      qh, ql, kh, kl, nullptr);

  // S3b: V plain GEMM (N=1024) -> vb
  gemm_kernel<4, false><<<dim3(1024/128, M/128), dim3(256), 0, stream>>>(
      zhi, nullptr, wqT_h + (size_t)2048*1024, nullptr, M, 1024, 1024,
      nullptr, nullptr, nullptr, nullptr,
      nullptr, nullptr, nullptr, nullptr, vb);

  // S3.5: Wout transpose (writes over dead zhi region)
  tsplit_kernel<false><<<dim3(1024/32, 1024/32), tb, 0, stream>>>(Wout, woT, nullptr, 1024, 1024);

  // S4: flash attention -> ctx (grid.x = nh for XCD L2 locality; 128 Q-rows/block)
  attn_kernel<<<dim3(64, 2048/128), dim3(512), 0, stream>>>(qh, ql, kh, kl, vb, mask, ctx);

  // S4.5: W1/W2 transposes (write over dead vb region — must follow attn)
  tsplit_kernel<false><<<dim3(4096/32, 1024/32), tb, 0, stream>>>(W1, w1T, nullptr, 1024, 4096);
  tsplit_kernel<false><<<dim3(1024/32, 4096/32), tb, 0, stream>>>(W2, w2T, nullptr, 4096, 1024);

  // S5: attn_out @ Wout + residual -> x2
  gemm_kernel<1, false><<<dim3(1024/128, M/128), dim3(256), 0, stream>>>(
      ctx, nullptr, woT, nullptr, M, 1024, 1024,
      x2, nullptr, x, nullptr,
      nullptr, nullptr, nullptr, nullptr, nullptr);

  // S6: LN2 -> z2
  ln_kernel<false><<<dim3(M), dim3(256), 0, stream>>>(x2, ln2g, ln2b, z2, nullptr);

  // S7: GELU(z2 @ W1 + b1) -> hbuf
  gemm_kernel<2, false><<<dim3(4096/128, M/128), dim3(256), 0, stream>>>(
      z2, nullptr, w1T, nullptr, M, 4096, 1024,
      nullptr, hbuf, nullptr, b1,
      nullptr, nullptr, nullptr, nullptr, nullptr);

  // S8: hbuf @ W2 + b2 + x2 -> out
  gemm_kernel<3, false><<<dim3(1024/128, M/128), dim3(256), 0, stream>>>(
      hbuf, nullptr, w2T, nullptr, M, 1024, 4096,
      out, nullptr, x2, b2,
      nullptr, nullptr, nullptr, nullptr, nullptr);
}